// Round 10
// baseline (888.678 us; speedup 1.0000x reference)
//
#include <hip/hip_runtime.h>
#include <cstdint>

// ---------- types / helpers ----------
typedef __attribute__((ext_vector_type(8))) short short8;
typedef __attribute__((ext_vector_type(4))) float f32x4;
typedef __attribute__((ext_vector_type(2))) float f32x2;
typedef __attribute__((ext_vector_type(4))) int i32x4;
typedef __attribute__((ext_vector_type(4))) float float4v;
typedef unsigned short us16;
typedef unsigned char u8;

#define DEV __device__ __forceinline__

DEV us16 f2bf(float f){
  union { float f; unsigned u; } v; v.f = f;
  unsigned r = (v.u + 0x7FFFu + ((v.u >> 16) & 1u)) >> 16;   // RNE
  return (us16)r;
}
DEV u8 f2fp8(float f){      // OCP e4m3fn via HW cvt (RNE, saturating)
  int p = __builtin_amdgcn_cvt_pk_fp8_f32(f, f, 0, false);
  return (u8)(p & 0xFF);
}
template<int SEL> DEV float fp8tof(int dw){
#if __has_builtin(__builtin_amdgcn_cvt_f32_fp8)
  return __builtin_amdgcn_cvt_f32_fp8(dw, SEL);
#else
  int b = (dw >> (8*SEL)) & 255;
  int e = (b>>3)&15, m = b&7;
  float v;
  if (e){ union{unsigned u; float f;} x; x.u = (unsigned)(((e+120)<<23) | (m<<20)); v = x.f; }
  else v = (float)m * 0.001953125f;
  return (b & 128) ? -v : v;
#endif
}
DEV f32x4 dq8x4(int dw){
#if __has_builtin(__builtin_amdgcn_cvt_pk_f32_fp8)
  f32x2 lo = __builtin_amdgcn_cvt_pk_f32_fp8(dw, false);
  f32x2 hi = __builtin_amdgcn_cvt_pk_f32_fp8(dw, true);
  return (f32x4){lo.x, lo.y, hi.x, hi.y};
#else
  return (f32x4){fp8tof<0>(dw), fp8tof<1>(dw), fp8tof<2>(dw), fp8tof<3>(dw)};
#endif
}
DEV float fsig(float x){
  float e = __builtin_amdgcn_exp2f(-1.4426950408889634f * x);
  return __builtin_amdgcn_rcpf(1.0f + e);
}
DEV float ftanh(float x){
  float e = __builtin_amdgcn_exp2f(-2.8853900817779268f * x);
  return fmaf(2.0f, __builtin_amdgcn_rcpf(1.0f + e), -1.0f);
}
DEV float fsoftplus(float x){
  float ax = fabsf(x);
  float e = __builtin_amdgcn_exp2f(-1.4426950408889634f * ax);
  float l = 0.69314718055994531f * __builtin_amdgcn_logf(1.0f + e);
  return fmaxf(x, 0.0f) + l;
}
DEV f32x4 mfma16f8(long a, long b, f32x4 c){
  return __builtin_amdgcn_mfma_f32_16x16x32_fp8_fp8(a, b, c, 0, 0, 0);
}
DEV unsigned pk4fp8(float a, float b, float c, float d){
  unsigned lo = (unsigned)__builtin_amdgcn_cvt_pk_fp8_f32(a, b, 0, false) & 0xFFFFu;
  unsigned hi = (unsigned)__builtin_amdgcn_cvt_pk_fp8_f32(c, d, 0, false) & 0xFFFFu;
  return lo | (hi << 16);
}
DEV int ld_acq(int* p){
  return __hip_atomic_load(p, __ATOMIC_ACQUIRE, __HIP_MEMORY_SCOPE_WORKGROUP);
}

// Dims: B=256, T=WN=200, HH=256/dir, gates=1024, tags K=12.
// MFMA 16x16x32 fragments: A: lane L holds A[m=L&15][k=(L>>4)*8+j];
// B: lane L holds B[k=(L>>4)*8+j][n=L&15]; D: lane L reg r = D[(L>>4)*4+r][L&15].
// pi h-permutation: orig col w*32+nt*16+l -> stored w*32+l*2+nt;
// inverse: s -> (s>>5)*32 + (s&1)*16 + ((s&31)>>1)
// KEY: stored h cols [kc*32,(kc+1)*32) are produced exactly by wave kc ->
// per-chunk dataflow flags can replace the per-step barrier in k_lstm.

// ---------- consolidated preprocessing (one launch) ----------

DEV void swz_lstm_one(int tid, const float* Whh, const float* Wih, int I, int KC, u8* dst){
  int e = tid & 511, chunk = tid >> 9;
  int L = e >> 3, j = e & 7;
  int kc = chunk % KC; int rem = chunk / KC;
  int nt = rem & 1, gt = (rem >> 1) & 3, w = rem >> 3;
  int g = gt * 256 + w * 32 + nt * 16 + (L & 15);
  int s = kc * 32 + (L >> 4) * 8 + j;
  float v = 0.0f;
  if (s < 256){
    int k = (s >> 5) * 32 + (s & 1) * 16 + ((s & 31) >> 1);
    v = Whh[g * 256 + k];
  } else {
    int xi = s - 256;
    if (xi < I) v = Wih[g * I + xi];
  }
  dst[tid] = f2fp8(v);
}
DEV void swz_ffB_one(int tid, const float* W, int N, int Kd, int KCs, int perm, u8* dst){
  int e = tid & 511, chunk = tid >> 9;
  int L = e >> 3, j = e & 7;
  int kc = chunk % KCs; int nt = chunk / KCs;
  int g = nt * 16 + (L & 15);
  int s = kc * 32 + (L >> 4) * 8 + j;
  int k;
  if (perm){ int base = s & ~255; int q = s & 255;
             k = base + (q >> 5) * 32 + (q & 1) * 16 + ((q & 31) >> 1); }
  else k = s;
  float v = (g < N && k < Kd) ? W[g * Kd + k] : 0.0f;
  dst[tid] = f2fp8(v);
}
DEV void swz_ffA_one(int tid, const float* W, int Kd, int KCs, u8* dst){
  int e = tid & 511, chunk = tid >> 9;
  int L = e >> 3, j = e & 7;
  int kc = chunk % KCs; int mt = chunk / KCs;
  int m = mt * 16 + (L & 15);
  int k = kc * 32 + (L >> 4) * 8 + j;
  float v = (k < Kd) ? W[m * Kd + k] : 0.0f;
  dst[tid] = f2fp8(v);
}

__global__ void k_prep(
    const int* __restrict__ chars, const float* __restrict__ emb, u8* __restrict__ cvec,
    const float* __restrict__ words, u8* __restrict__ wf8,
    const float* __restrict__ cWhf, const float* __restrict__ cWif, u8* wcf,
    const float* __restrict__ cWhb, const float* __restrict__ cWib, u8* wcb,
    const float* __restrict__ wWhf, u8* wwf, const float* __restrict__ wWhb, u8* wwb,
    const float* __restrict__ wWif, const float* __restrict__ wWib, u8* gf, u8* gb,
    const float* __restrict__ W1, u8* d1, const float* __restrict__ W2, u8* d2,
    const float* __restrict__ W5, u8* d5,
    const float* __restrict__ W3, u8* d3, const float* __restrict__ W4, u8* d4)
{
  int b = blockIdx.x, t = threadIdx.x;
  if (b < 6400){                               // char embed -> fp8
    int tid = b * 256 + t;
    int c = tid & 31, bt = tid >> 5;
    int idx = chars[bt];
    float v = (c < 30) ? emb[idx * 30 + c] : 0.0f;
    cvec[tid] = f2fp8(v);
  } else if (b < 12800){                       // words fp32 -> fp8, x4
    int i = (b - 6400) * 256 + t;
    float4v v = *(const float4v*)&words[(long)i * 4];
    *(unsigned*)&wf8[(long)i * 4] = pk4fp8(v.x, v.y, v.z, v.w);
  } else if (b < 17152){
    int bb = b - 12800;
    if (bb < 1152)      swz_lstm_one(bb * 256 + t, cWhf, cWif, 30, 9, wcf);
    else if (bb < 2304) swz_lstm_one((bb - 1152) * 256 + t, cWhb, cWib, 30, 9, wcb);
    else if (bb < 3328) swz_lstm_one((bb - 2304) * 256 + t, wWhf, nullptr, 0, 8, wwf);
    else                swz_lstm_one((bb - 3328) * 256 + t, wWhb, nullptr, 0, 8, wwb);
  } else if (b < 18176){                       // word Wih B-frag (gin weights)
    int bb = b - 17152;
    const float* W = (bb < 512) ? wWif : wWib;
    u8* dst = (bb < 512) ? gf : gb;
    int tid = ((bb < 512) ? bb : bb - 512) * 256 + t;
    int e = tid & 511, chunk = tid >> 9;
    int L = e >> 3, j = e & 7;
    int kc = chunk & 3, ntile = chunk >> 2;
    int g = ntile * 16 + (L & 15);
    int k = kc * 32 + (L >> 4) * 8 + j;
    dst[tid] = f2fp8(W[g * 128 + k]);
  } else if (b < 19728){
    int bb = b - 18176;
    if (bb < 1024)      swz_ffB_one(bb * 256 + t, W1, 512, 512, 16, 1, d1);
    else if (bb < 1536) swz_ffB_one((bb - 1024) * 256 + t, W2, 200, 512, 16, 1, d2);
    else                swz_ffB_one((bb - 1536) * 256 + t, W5, 12, 256, 8, 0, d5);
  } else {
    int bb = b - 19728;
    if (bb < 1536) swz_ffA_one(bb * 256 + t, W3, 712, 24, d3);
    else           swz_ffA_one((bb - 1536) * 256 + t, W4, 512, 16, d4);
  }
}

// ---------- gin precompute: gin = fp8(x @ Wih^T + b), 4 timesteps/block ----------
__global__ __launch_bounds__(512) void k_gin(
    const u8* __restrict__ words_f8, const u8* __restrict__ wswg_f,
    const u8* __restrict__ wswg_b, const float* __restrict__ bias_f,
    const float* __restrict__ bias_b, u8* __restrict__ gin)
{
  const int blk = blockIdx.x;
  const int d = blk / 800, rem = blk - d * 800;
  const int slice = rem / 50, tq = rem - slice * 50;
  const u8* Wsw = d ? wswg_b : wswg_f;
  const float* bias = d ? bias_b : bias_f;
  __shared__ u8 xs[16 * 136];
  __shared__ u8 sbuf[512 * 32];
  const int tid = threadIdx.x;
  const int wv = tid >> 6, L = tid & 63;
  const int lrow = L & 15, lq = L >> 4;
  const long* WswV = (const long*)Wsw;

  long wr[8][4];
  #pragma unroll
  for (int nt = 0; nt < 8; ++nt)
    #pragma unroll
    for (int kc = 0; kc < 4; ++kc)
      wr[nt][kc] = WswV[((wv * 8 + nt) * 4 + kc) * 64 + L];
  float bv[8];
  #pragma unroll
  for (int nt = 0; nt < 8; ++nt) bv[nt] = bias[wv * 128 + nt * 16 + lrow];

  for (int i = 0; i < 4; ++i){
    const int t = tq * 4 + i;
    if (tid < 256){
      int r = tid >> 4, c8 = (tid & 15) * 8;
      *(long*)&xs[r * 136 + c8] =
        *(const long*)&words_f8[((long)(slice * 16 + r) * 200 + t) * 128 + c8];
    }
    __syncthreads();
    f32x4 acc[8];
    #pragma unroll
    for (int nt = 0; nt < 8; ++nt) acc[nt] = (f32x4){bv[nt], bv[nt], bv[nt], bv[nt]};
    #pragma unroll
    for (int kc = 0; kc < 4; ++kc){
      long af = *(const long*)&xs[lrow * 136 + kc * 32 + lq * 8];
      #pragma unroll
      for (int nt = 0; nt < 8; ++nt)
        acc[nt] = mfma16f8(af, wr[nt][kc], acc[nt]);
    }
    #pragma unroll
    for (int nt = 0; nt < 8; ++nt){
      int gcol = wv * 128 + nt * 16 + lrow;
      int gt = gcol >> 8, w2 = (gcol >> 5) & 7, nt2 = (gcol >> 4) & 1;
      int tid2 = w2 * 64 + lq * 16 + lrow;
      #pragma unroll
      for (int r = 0; r < 4; ++r)
        sbuf[tid2 * 32 + gt * 8 + nt2 * 4 + r] = f2fp8(acc[nt][r]);
    }
    __syncthreads();
    long ob = (((long)(d * 16 + slice) * 200 + t) * 512 + tid) * 32;
    *(i32x4*)&gin[ob]      = *(const i32x4*)&sbuf[tid * 32];
    *(i32x4*)&gin[ob + 16] = *(const i32x4*)&sbuf[tid * 32 + 16];
    __syncthreads();
  }
}

// ---------- bidirectional LSTM: barrier-free dataflow loop ----------
// 64 blocks x 512 thr. prod[w] = steps published by wave w; done = total
// read-phases completed. Chunk kc's data is produced by wave kc only.
// Waves read chunks in rotated order (own first); weights pre-rotated so all
// register indices are static. Double buffer gives exactly 1 step of slack.
template<int KC, int XDIM, int SA, bool GIN>
DEV void lstm_body(u8* abuf, int* prod, int* done,
                   const u8* __restrict__ xbuf, const u8* __restrict__ gin,
                   const u8* __restrict__ Wsw, const float* __restrict__ bias,
                   const int* __restrict__ lens, u8* __restrict__ hout,
                   int b0, int hcol0, bool rev, long ginBase)
{
  constexpr int BUF = 16 * SA;
  const int tid = threadIdx.x;
  const int w = tid >> 6, L = tid & 63;
  const int lrow = L & 15, lq = L >> 4;
  const long* WswV = (const long*)Wsw;

  // resident weights, pre-rotated: slot i holds chunk (w+i)&7 (i<8), slot 8 = x
  int kcs[KC];
  #pragma unroll
  for (int i = 0; i < KC; ++i) kcs[i] = (i < 8) ? ((w + i) & 7) : 8;
  long wr[4][2][KC];
  #pragma unroll
  for (int gt = 0; gt < 4; ++gt)
    #pragma unroll
    for (int nt = 0; nt < 2; ++nt)
      #pragma unroll
      for (int i = 0; i < KC; ++i)
        wr[gt][nt][i] = WswV[(((w * 4 + gt) * 2 + nt) * KC + kcs[i]) * 64 + L];

  float bv[4][2];
  if constexpr (!GIN){
    #pragma unroll
    for (int gt = 0; gt < 4; ++gt)
      #pragma unroll
      for (int nt = 0; nt < 2; ++nt)
        bv[gt][nt] = bias[gt * 256 + w * 32 + nt * 16 + lrow];
  }

  unsigned lpack = 0;
  #pragma unroll
  for (int r = 0; r < 4; ++r)
    lpack |= (unsigned)lens[b0 + lq * 4 + r] << (8 * r);

  float cst[2][4];
  us16 hst[4];
  #pragma unroll
  for (int r = 0; r < 4; ++r){ hst[r] = 0; cst[0][r] = 0.0f; cst[1][r] = 0.0f; }

  if (tid < 8) prod[tid] = 0;
  if (tid == 8) *done = 0;
  for (int e = tid; e < 16 * 32; e += 512)
    *(long*)&abuf[(e >> 5) * SA + (e & 31) * 8] = 0;

  const int t0 = rev ? 199 : 0;
  if constexpr (!GIN){
    if (tid < (16 * XDIM) >> 3){
      int r = tid / (XDIM >> 3), c8 = (tid % (XDIM >> 3)) * 8;
      *(long*)&abuf[r * SA + 256 + c8] =
        *(const long*)&xbuf[((long)(b0 + r) * 200 + t0) * XDIM + c8];
    }
  }
  i32x4 gA{}, gB{};
  if constexpr (GIN){
    const u8* gp = gin + ((ginBase + t0) * 512 + tid) * 32;
    gA = *(const i32x4*)gp; gB = *(const i32x4*)(gp + 16);
  }
  __syncthreads();                       // one-time init barrier

  for (int tau = 0; tau < 200; ++tau){
    const int t = rev ? (199 - tau) : tau;
    u8* cur = abuf + (tau & 1) * BUF;
    u8* nxt = abuf + ((tau & 1) ^ 1) * BUF;

    f32x4 acc[4][2];
    if constexpr (GIN){
      int g4[8];
      *(i32x4*)&g4[0] = gA; *(i32x4*)&g4[4] = gB;
      #pragma unroll
      for (int gt = 0; gt < 4; ++gt)
        #pragma unroll
        for (int nt = 0; nt < 2; ++nt)
          acc[gt][nt] = dq8x4(g4[gt * 2 + nt]);
      int tn = (tau < 199) ? (rev ? 198 - tau : tau + 1) : t;
      const u8* gp = gin + ((ginBase + tn) * 512 + tid) * 32;
      gA = *(const i32x4*)gp; gB = *(const i32x4*)(gp + 16);
    } else {
      #pragma unroll
      for (int gt = 0; gt < 4; ++gt)
        #pragma unroll
        for (int nt = 0; nt < 2; ++nt)
          acc[gt][nt] = (f32x4){bv[gt][nt], bv[gt][nt], bv[gt][nt], bv[gt][nt]};
    }

    // read phase: chunk i's producer is wave kcs[i] (i<8); chunk 8 (x) is
    // staged by wave 0 and published with prod[0].
    #pragma unroll
    for (int i = 0; i < KC; ++i){
      if (i >= 1 && i < 8){
        int* fp = &prod[kcs[i]];
        while (ld_acq(fp) < tau) __builtin_amdgcn_s_sleep(0);
      }
      long af = *(const long*)&cur[lrow * SA + kcs[i] * 32 + lq * 8];
      #pragma unroll
      for (int gt = 0; gt < 4; ++gt)
        #pragma unroll
        for (int nt = 0; nt < 2; ++nt)
          acc[gt][nt] = mfma16f8(af, wr[gt][nt][i], acc[gt][nt]);
    }
    __threadfence_block();               // prior ds_reads complete
    if (L == 0)
      __hip_atomic_fetch_add(done, 1, __ATOMIC_RELEASE, __HIP_MEMORY_SCOPE_WORKGROUP);
    // write permission: all waves finished reading the buffer we overwrite
    while (ld_acq(done) < 8 * tau) __builtin_amdgcn_s_sleep(0);

    // epilogue: packed fp8 pair per r -> nxt LDS
    us16 houtv[4];
    #pragma unroll
    for (int r = 0; r < 4; ++r){
      const int bm = lq * 4 + r;
      const bool mk = t < (int)((lpack >> (8 * r)) & 255u);
      float hnv[2];
      #pragma unroll
      for (int nt = 0; nt < 2; ++nt){
        float gi = acc[0][nt][r], gf = acc[1][nt][r];
        float gg = acc[2][nt][r], go = acc[3][nt][r];
        float cn = fsig(gf) * cst[nt][r] + fsig(gi) * ftanh(gg);
        if (mk) cst[nt][r] = cn;
        hnv[nt] = fsig(go) * ftanh(cn);
      }
      int pk = __builtin_amdgcn_cvt_pk_fp8_f32(hnv[0], hnv[1], 0, false);
      us16 p16 = (us16)(pk & 0xFFFF);
      if (mk) hst[r] = p16;
      houtv[r] = mk ? p16 : (us16)0;
      *(us16*)&nxt[bm * SA + w * 32 + lrow * 2] = hst[r];
    }
    if constexpr (!GIN){
      if (tau < 199){
        int tn = rev ? (198 - tau) : (tau + 1);
        if (tid < (16 * XDIM) >> 3){     // wave 0 stages x for next step
          int r = tid / (XDIM >> 3), c8 = (tid % (XDIM >> 3)) * 8;
          *(long*)&nxt[r * SA + 256 + c8] =
            *(const long*)&xbuf[((long)(b0 + r) * 200 + tn) * XDIM + c8];
        }
      }
    }
    __threadfence_block();               // h (+x) visible before publish
    if (L == 0)
      __hip_atomic_store(&prod[w], tau + 1, __ATOMIC_RELEASE, __HIP_MEMORY_SCOPE_WORKGROUP);

    // global h stores retire in background (no barrier drain anywhere)
    #pragma unroll
    for (int r = 0; r < 4; ++r){
      const int bm = lq * 4 + r;
      long ga = ((long)(b0 + bm) * 200 + t) * 512 + hcol0 + w * 32 + lrow * 2;
      *(us16*)&hout[ga] = houtv[r];
    }
  }
}

__global__ __launch_bounds__(512, 2) void k_lstm(
    const u8* __restrict__ char_vec, const u8* __restrict__ gin,
    const u8* __restrict__ wsw_cf, const u8* __restrict__ wsw_cb,
    const u8* __restrict__ wsw_wf, const u8* __restrict__ wsw_wb,
    const float* __restrict__ b_cf, const float* __restrict__ b_cb,
    const int* __restrict__ len_char, const int* __restrict__ len_word,
    u8* __restrict__ h_char, u8* __restrict__ h_word)
{
  const int dir   = blockIdx.x >> 4;
  const int slice = blockIdx.x & 15;
  const int b0 = slice * 16;
  __shared__ __align__(16) u8 abuf[2 * 16 * 304];
  __shared__ int prod[8];
  __shared__ int done;

  if (dir == 0)
    lstm_body<9, 32, 304, false>(abuf, prod, &done, char_vec, nullptr, wsw_cf, b_cf,
                                 len_char, h_char, b0, 0, false, 0);
  else if (dir == 1)
    lstm_body<9, 32, 304, false>(abuf, prod, &done, char_vec, nullptr, wsw_cb, b_cb,
                                 len_char, h_char, b0, 256, true, 0);
  else if (dir == 2)
    lstm_body<8, 0, 280, true>(abuf, prod, &done, nullptr, gin, wsw_wf, nullptr,
                               len_word, h_word, b0, 0, false, (long)slice * 200);
  else
    lstm_body<8, 0, 280, true>(abuf, prod, &done, nullptr, gin, wsw_wb, nullptr,
                               len_word, h_word, b0, 256, true, (long)(16 + slice) * 200);
}

// ---------- G1+G2 merged (fp8 GEMM into x_cat, zero-fill pad cols) ----------
DEV void g12_body(const u8* __restrict__ A, const u8* __restrict__ Wsw,
                  const float* __restrict__ bias, int N,
                  u8* __restrict__ outp, int ocol0, int m0base, int ntbase, u8* lds)
{
  const int tid = threadIdx.x;
  const int w = tid >> 6, L = tid & 63;
  const int lrow = L & 15, lq = L >> 4;
  const long* WswV = (const long*)Wsw;
  f32x4 acc[8][2] = {};
  const int srow = tid >> 1, scol = (tid & 1) * 32;

  for (int kc2 = 0; kc2 < 8; ++kc2){
    const long ab = (long)(m0base + srow) * 512 + kc2 * 64 + scol;
    i32x4 v0 = *(const i32x4*)&A[ab];
    i32x4 v1 = *(const i32x4*)&A[ab + 16];
    *(long*)&lds[srow * 72 + scol]      = ((const long*)&v0)[0];
    *(long*)&lds[srow * 72 + scol + 8]  = ((const long*)&v0)[1];
    *(long*)&lds[srow * 72 + scol + 16] = ((const long*)&v1)[0];
    *(long*)&lds[srow * 72 + scol + 24] = ((const long*)&v1)[1];
    __syncthreads();
    long af[2][2];
    #pragma unroll
    for (int m0 = 0; m0 < 2; ++m0)
      #pragma unroll
      for (int kk = 0; kk < 2; ++kk)
        af[m0][kk] = *(const long*)&lds[(w * 32 + m0 * 16 + lrow) * 72 + kk * 32 + lq * 8];
    #pragma unroll
    for (int kk = 0; kk < 2; ++kk)
      #pragma unroll
      for (int nt = 0; nt < 8; ++nt){
        long bf = WswV[((ntbase + nt) * 16 + kc2 * 2 + kk) * 64 + L];
        acc[nt][0] = mfma16f8(af[0][kk], bf, acc[nt][0]);
        acc[nt][1] = mfma16f8(af[1][kk], bf, acc[nt][1]);
      }
    __syncthreads();
  }
  #pragma unroll
  for (int nt = 0; nt < 8; ++nt){
    const int col = (ntbase + nt) * 16 + lrow;
    const bool valid = col < N;
    const float bvv = valid ? bias[col] : 0.0f;
    #pragma unroll
    for (int m0 = 0; m0 < 2; ++m0){
      #pragma unroll
      for (int r = 0; r < 4; ++r){
        float v = fsoftplus(acc[nt][m0][r] + bvv);
        const long row = m0base + w * 32 + m0 * 16 + lq * 4 + r;
        outp[row * 768 + ocol0 + col] = valid ? f2fp8(v) : (u8)0;
      }
    }
  }
}

__global__ __launch_bounds__(256) void k_g12(
    const u8* __restrict__ hc, const u8* __restrict__ hw,
    const u8* __restrict__ w1, const u8* __restrict__ w2,
    const float* __restrict__ b1, const float* __restrict__ b2,
    u8* __restrict__ xcat)
{
  __shared__ __align__(16) u8 lds[128 * 72];
  const int y = blockIdx.y;
  if (y < 4)
    g12_body(hc, w1, b1, 512, xcat,   0, blockIdx.x * 128, y * 8, lds);
  else
    g12_body(hw, w2, b2, 200, xcat, 512, blockIdx.x * 128, (y - 4) * 8, lds);
}

// ---------- fused tail: logits = sp(sp(sp(xcat@W3+b3)@W4+b4)@W5+b5) ----------
__global__ __launch_bounds__(256, 2) void k_tail(
    const u8* __restrict__ xcat, const u8* __restrict__ w3A,
    const u8* __restrict__ w4A, const u8* __restrict__ w5B,
    const float* __restrict__ b3, const float* __restrict__ b4,
    const float* __restrict__ b5, float* __restrict__ logits)
{
  __shared__ __align__(16) u8 sA[64 * 72];
  __shared__ __align__(16) u8 x1s[64 * 520];
  __shared__ __align__(16) u8 x2s[64 * 264];
  const int tid = threadIdx.x;
  const int w = tid >> 6, L = tid & 63;
  const int lrow = L & 15, lq = L >> 4;
  const int m0 = blockIdx.x * 64;
  const long* W3 = (const long*)w3A;
  const long* W4 = (const long*)w4A;
  const long* W5 = (const long*)w5B;

  // stage 1: A=W3, B=xcat, D=x1^T
  f32x4 acc[8][4];
  #pragma unroll
  for (int mt = 0; mt < 8; ++mt)
    #pragma unroll
    for (int nt = 0; nt < 4; ++nt) acc[mt][nt] = (f32x4){0,0,0,0};
  const int srow = tid >> 2, sc = (tid & 3) * 16;

  for (int kc2 = 0; kc2 < 12; ++kc2){
    i32x4 v = *(const i32x4*)&xcat[(long)(m0 + srow) * 768 + kc2 * 64 + sc];
    *(long*)&sA[srow * 72 + sc]     = ((const long*)&v)[0];
    *(long*)&sA[srow * 72 + sc + 8] = ((const long*)&v)[1];
    __syncthreads();
    #pragma unroll
    for (int kk = 0; kk < 2; ++kk){
      long bf[4];
      #pragma unroll
      for (int nt = 0; nt < 4; ++nt)
        bf[nt] = *(const long*)&sA[(nt * 16 + lrow) * 72 + kk * 32 + lq * 8];
      #pragma unroll
      for (int mt = 0; mt < 8; ++mt){
        long af = W3[((w * 8 + mt) * 24 + kc2 * 2 + kk) * 64 + L];
        #pragma unroll
        for (int nt = 0; nt < 4; ++nt)
          acc[mt][nt] = mfma16f8(af, bf[nt], acc[mt][nt]);
      }
    }
    __syncthreads();
  }
  #pragma unroll
  for (int mt = 0; mt < 8; ++mt){
    const int ch0 = (w * 8 + mt) * 16 + lq * 4;
    f32x4 bb = *(const f32x4*)&b3[ch0];
    #pragma unroll
    for (int nt = 0; nt < 4; ++nt){
      const int bat = nt * 16 + lrow;
      unsigned pk = pk4fp8(fsoftplus(acc[mt][nt][0] + bb[0]),
                           fsoftplus(acc[mt][nt][1] + bb[1]),
                           fsoftplus(acc[mt][nt][2] + bb[2]),
                           fsoftplus(acc[mt][nt][3] + bb[3]));
      *(unsigned*)&x1s[bat * 520 + ch0] = pk;
    }
  }
  __syncthreads();

  // stage 2: A=W4, B=x1, D=x2^T
  f32x4 a2[4][4];
  #pragma unroll
  for (int mt = 0; mt < 4; ++mt)
    #pragma unroll
    for (int nt = 0; nt < 4; ++nt) a2[mt][nt] = (f32x4){0,0,0,0};
  for (int kc = 0; kc < 16; ++kc){
    long bf[4];
    #pragma unroll
    for (int nt = 0; nt < 4; ++nt)
      bf[nt] = *(const long*)&x1s[(nt * 16 + lrow) * 520 + kc * 32 + lq * 8];
    #pragma unroll
    for (int mt = 0; mt < 4; ++mt){
      long af = W4[((w * 4 + mt) * 16 + kc) * 64 + L];
      #pragma unroll
      for (int nt = 0; nt < 4; ++nt)
        a2[mt][nt] = mfma16f8(af, bf[nt], a2[mt][nt]);
    }
  }
  #pragma unroll
  for (int mt = 0; mt < 4; ++mt){
    const int ch0 = (w * 4 + mt) * 16 + lq * 4;
    f32x4 bb = *(const f32x4*)&b4[ch0];
    #pragma unroll
    for (int nt = 0; nt < 4; ++nt){
      const int bat = nt * 16 + lrow;
      unsigned pk = pk4fp8(fsoftplus(a2[mt][nt][0] + bb[0]),
                           fsoftplus(a2[mt][nt][1] + bb[1]),
                           fsoftplus(a2[mt][nt][2] + bb[2]),
                           fsoftplus(a2[mt][nt][3] + bb[3]));
      *(unsigned*)&x2s[bat * 264 + ch0] = pk;
    }
  }
  __syncthreads();

  // stage 3: logits (normal roles)
  f32x4 a3 = (f32x4){0,0,0,0};
  #pragma unroll
  for (int kc = 0; kc < 8; ++kc){
    long af = *(const long*)&x2s[(w * 16 + lrow) * 264 + kc * 32 + lq * 8];
    long bf = W5[kc * 64 + L];
    a3 = mfma16f8(af, bf, a3);
  }
  if (lrow < 12){
    float bb = b5[lrow];
    #pragma unroll
    for (int r = 0; r < 4; ++r)
      logits[(long)(m0 + w * 16 + lq * 4 + r) * 12 + lrow] = fsoftplus(a3[r] + bb);
  }
}

// ---------- CRF NLL ----------
__global__ void k_crf(const float* __restrict__ logits, const int* __restrict__ tags,
                      const int* __restrict__ lens, const float* __restrict__ trans,
                      float* __restrict__ nll)
{
  const int b = blockIdx.x;
  const int lane = threadIdx.x;            // 64
  __shared__ float sl[2400];
  __shared__ float alpha[12];
  __shared__ float tmp[12];
  for (int e = lane; e < 2400; e += 64) sl[e] = logits[(long)b * 2400 + e];
  float tcol[12];
  if (lane < 12){
    #pragma unroll
    for (int i = 0; i < 12; ++i) tcol[i] = trans[i * 12 + lane];
    alpha[lane] = 0.0f;
  }
  const int len = lens[b];
  __syncthreads();
  for (int t = 0; t < len; ++t){
    float an = 0.0f;
    if (lane < 12){
      float mx = -3.0e38f;
      #pragma unroll
      for (int i = 0; i < 12; ++i) mx = fmaxf(mx, alpha[i] + tcol[i]);
      float ss = 0.0f;
      #pragma unroll
      for (int i = 0; i < 12; ++i)
        ss += __builtin_amdgcn_exp2f(1.4426950408889634f * (alpha[i] + tcol[i] - mx));
      an = sl[t * 12 + lane] + mx + 0.69314718055994531f * __builtin_amdgcn_logf(ss);
    }
    __syncthreads();
    if (lane < 12) alpha[lane] = an;
    __syncthreads();
  }
  if (lane < 12) tmp[lane] = alpha[lane] + trans[lane * 12 + 11];
  __syncthreads();
  float rs = 0.0f;
  for (int t = lane; t < len; t += 64){
    int tg = tags[b * 200 + t];
    int pv = (t == 0) ? 10 : tags[b * 200 + t - 1];                 // START=10
    rs += sl[t * 12 + tg] + trans[pv * 12 + tg];
  }
  #pragma unroll
  for (int off = 32; off > 0; off >>= 1) rs += __shfl_down(rs, off, 64);
  if (lane == 0){
    float mx = -3.0e38f;
    for (int i = 0; i < 12; ++i) mx = fmaxf(mx, tmp[i]);
    float ss = 0.0f;
    for (int i = 0; i < 12; ++i)
      ss += __builtin_amdgcn_exp2f(1.4426950408889634f * (tmp[i] - mx));
    float total = mx + 0.69314718055994531f * __builtin_amdgcn_logf(ss);
    rs += trans[tags[b * 200 + len - 1] * 12 + 11];
    nll[b] = total - rs;
  }
}

__global__ void k_sum(const float* __restrict__ nll, float* __restrict__ out){
  __shared__ float red[256];
  int t = threadIdx.x;
  red[t] = nll[t];
  __syncthreads();
  for (int s = 128; s > 0; s >>= 1){
    if (t < s) red[t] += red[t + s];
    __syncthreads();
  }
  if (t == 0) out[0] = red[0];
}

// ---------- launcher ----------
extern "C" void kernel_launch(void* const* d_in, const int* in_sizes, int n_in,
                              void* d_out, int out_size, void* d_ws, size_t ws_size,
                              hipStream_t stream)
{
  (void)in_sizes; (void)n_in; (void)out_size; (void)ws_size;
  const int*   characters = (const int*)  d_in[0];
  const float* words      = (const float*)d_in[1];
  const int*   tags       = (const int*)  d_in[2];
  const int*   len_char   = (const int*)  d_in[3];
  const int*   len_word   = (const int*)  d_in[4];
  const float* char_emb   = (const float*)d_in[5];
  const float* char_Wih_f = (const float*)d_in[6];
  const float* char_Whh_f = (const float*)d_in[7];
  const float* char_b_f   = (const float*)d_in[8];
  const float* char_Wih_b = (const float*)d_in[9];
  const float* char_Whh_b = (const float*)d_in[10];
  const float* char_b_b   = (const float*)d_in[11];
  const float* char_lin_W = (const float*)d_in[12];
  const float* char_lin_b = (const float*)d_in[13];
  const float* word_Wih_f = (const float*)d_in[14];
  const float* word_Whh_f = (const float*)d_in[15];
  const float* word_b_f   = (const float*)d_in[16];
  const float* word_Wih_b = (const float*)d_in[17];
  const float* word_Whh_b = (const float*)d_in[18];
  const float* word_b_b   = (const float*)d_in[19];
  const float* word_lin_W = (const float*)d_in[20];
  const float* word_lin_b = (const float*)d_in[21];
  const float* lin1_W     = (const float*)d_in[22];
  const float* lin1_b     = (const float*)d_in[23];
  const float* lin2_W     = (const float*)d_in[24];
  const float* lin2_b     = (const float*)d_in[25];
  const float* tag_W      = (const float*)d_in[26];
  const float* tag_b      = (const float*)d_in[27];
  const float* trans      = (const float*)d_in[28];

  char* ws = (char*)d_ws;
  size_t off = 0;
  auto take = [&](size_t bytes) -> char* {
    char* p = ws + off;
    off = (off + bytes + 511) & ~(size_t)511;
    return p;
  };
  u8*   char_vec = (u8*)take((size_t)256*200*32);
  u8*   words_f8 = (u8*)take((size_t)256*200*128);
  u8*   wsw_cf   = (u8*)take((size_t)64*9*512);
  u8*   wsw_cb   = (u8*)take((size_t)64*9*512);
  u8*   wsw_wf   = (u8*)take((size_t)64*8*512);
  u8*   wsw_wb   = (u8*)take((size_t)64*8*512);
  u8*   wswgin_f = (u8*)take((size_t)64*4*512);
  u8*   wswgin_b = (u8*)take((size_t)64*4*512);
  u8*   wswg1    = (u8*)take((size_t)32*16*512);
  u8*   wswg2    = (u8*)take((size_t)16*16*512);
  u8*   wswg3    = (u8*)take((size_t)32*24*512);
  u8*   wswg4    = (u8*)take((size_t)16*16*512);
  u8*   wswg5    = (u8*)take((size_t)1*8*512);
  float* logits  = (float*)take((size_t)51200*12*4);
  float* nll     = (float*)take((size_t)256*4);
  u8*   h_char   = (u8*)take((size_t)51200*512);
  u8*   h_word   = (u8*)take((size_t)51200*512);
  u8*   gin      = (u8*)take((size_t)105*1024*1024);
  u8*   x_cat    = gin;                            // 38.4 MB, written after k_lstm

  // consolidated preprocessing (one launch)
  k_prep<<<21776, 256, 0, stream>>>(
      characters, char_emb, char_vec, words, words_f8,
      char_Whh_f, char_Wih_f, wsw_cf, char_Whh_b, char_Wih_b, wsw_cb,
      word_Whh_f, wsw_wf, word_Whh_b, wsw_wb,
      word_Wih_f, word_Wih_b, wswgin_f, wswgin_b,
      char_lin_W, wswg1, word_lin_W, wswg2, tag_W, wswg5,
      lin1_W, wswg3, lin2_W, wswg4);

  // gin precompute
  k_gin<<<1600, 512, 0, stream>>>(words_f8, wswgin_f, wswgin_b, word_b_f, word_b_b, gin);

  // recurrences (barrier-free dataflow)
  k_lstm<<<64, 512, 0, stream>>>(char_vec, gin, wsw_cf, wsw_cb, wsw_wf, wsw_wb,
                                 char_b_f, char_b_b, len_char, len_word, h_char, h_word);

  // feed-forward
  k_g12<<<dim3(400, 6), 256, 0, stream>>>(h_char, h_word, wswg1, wswg2,
                                          char_lin_b, word_lin_b, x_cat);
  k_tail<<<800, 256, 0, stream>>>(x_cat, wswg3, wswg4, wswg5,
                                  lin1_b, lin2_b, tag_b, logits);

  // CRF
  k_crf<<<256, 64, 0, stream>>>(logits, tags, len_char, trans, nll);
  k_sum<<<1, 256, 0, stream>>>(nll, (float*)d_out);
}